// Round 15
// baseline (101.918 us; speedup 1.0000x reference)
//
#include <hip/hip_runtime.h>
#include <cstdint>
#include <cstddef>

typedef unsigned short u16;
typedef __attribute__((ext_vector_type(8))) short bf16x8;
typedef __attribute__((ext_vector_type(8))) unsigned short u16x8;
typedef __attribute__((ext_vector_type(4))) unsigned short u16x4;
typedef __attribute__((ext_vector_type(4))) float f32x4;

// ---------- helpers ----------
__device__ __forceinline__ u16 f2b(float f) {
    union { float f; uint32_t u; } v; v.f = f;
    uint32_t u = v.u;
    uint32_t r = (u + 0x7FFFu + ((u >> 16) & 1u)) >> 16;
    return (u16)r;
}
__device__ __forceinline__ float b2f(u16 b) {
    union { uint32_t u; float f; } v; v.u = ((uint32_t)b) << 16;
    return v.f;
}
__device__ __forceinline__ void gload_lds16(const void* g, void* l) {
    __builtin_amdgcn_global_load_lds(
        (const __attribute__((address_space(1))) void*)g,
        (__attribute__((address_space(3))) void*)l,
        16, 0, 0);
}

// ---------- prep building blocks ----------
__device__ __forceinline__ void cvt_fat(const float* __restrict__ in,
                                        u16* __restrict__ outp, int bb, int tid) {
#pragma unroll
    for (int it = 0; it < 8; ++it) {
        size_t u = (size_t)bb * 2048 + (size_t)it * 256 + tid;
        size_t base = u * 8;
        const float4* p = (const float4*)(in + base);
        float4 a = p[0], c = p[1];
        u16x8 o;
        o[0] = f2b(a.x); o[1] = f2b(a.y); o[2] = f2b(a.z); o[3] = f2b(a.w);
        o[4] = f2b(c.x); o[5] = f2b(c.y); o[6] = f2b(c.z); o[7] = f2b(c.w);
        *(u16x8*)(outp + base) = o;
    }
}

__device__ __forceinline__ void transpose64_256(const float* __restrict__ in,
                                                u16* __restrict__ outp,
                                                int K, int N, int t, int tid,
                                                float (*tile)[65]) {
    const int ntx = N >> 6;
    const int n0 = (t % ntx) * 64, k0 = (t / ntx) * 64;
    const int r0 = tid >> 4, c4 = tid & 15;
#pragma unroll
    for (int j = 0; j < 4; ++j) {
        int r = r0 + j * 16;
        float4 v = *(const float4*)(in + (size_t)(k0 + r) * N + n0 + c4 * 4);
        tile[r][c4 * 4 + 0] = v.x; tile[r][c4 * 4 + 1] = v.y;
        tile[r][c4 * 4 + 2] = v.z; tile[r][c4 * 4 + 3] = v.w;
    }
    __syncthreads();
    const int rr = tid >> 2;
#pragma unroll
    for (int j = 0; j < 4; ++j) {
        int ch = (tid & 3) + j * 4;
        u16x4 o;
        o[0] = f2b(tile[ch * 4 + 0][rr]); o[1] = f2b(tile[ch * 4 + 1][rr]);
        o[2] = f2b(tile[ch * 4 + 2][rr]); o[3] = f2b(tile[ch * 4 + 3][rr]);
        *(u16x4*)(outp + (size_t)(n0 + rr) * K + k0 + ch * 4) = o;
    }
    __syncthreads();
}

__device__ __forceinline__ void transpose64_512(const float* __restrict__ in,
                                                u16* __restrict__ outp,
                                                int K, int N, int t, int tid,
                                                float (*tile)[65]) {
    const int ntx = N >> 6;
    const int n0 = (t % ntx) * 64, k0 = (t / ntx) * 64;
    const int r0 = tid >> 4, c4 = tid & 15;
#pragma unroll
    for (int j = 0; j < 2; ++j) {
        int r = r0 + j * 32;
        float4 v = *(const float4*)(in + (size_t)(k0 + r) * N + n0 + c4 * 4);
        tile[r][c4 * 4 + 0] = v.x; tile[r][c4 * 4 + 1] = v.y;
        tile[r][c4 * 4 + 2] = v.z; tile[r][c4 * 4 + 3] = v.w;
    }
    __syncthreads();
    const int rr = tid >> 3;
#pragma unroll
    for (int j = 0; j < 2; ++j) {
        int ch = (tid & 7) + j * 8;
        u16x4 o;
        o[0] = f2b(tile[ch * 4 + 0][rr]); o[1] = f2b(tile[ch * 4 + 1][rr]);
        o[2] = f2b(tile[ch * 4 + 2][rr]); o[3] = f2b(tile[ch * 4 + 3][rr]);
        *(u16x4*)(outp + (size_t)(n0 + rr) * K + k0 + ch * 4) = o;
    }
    __syncthreads();
}

// ---------- prep1 (256 thr, 576 blocks) — round-12-verified ----------
__global__ __launch_bounds__(256) void prep1_kernel(
    const float* __restrict__ feat, u16* __restrict__ featB,
    const float* __restrict__ W1, u16* __restrict__ W1T,
    const float* __restrict__ W3, u16* __restrict__ W3c,
    const float* __restrict__ Wh, u16* __restrict__ WhT,
    const float* __restrict__ b3, const float* __restrict__ bh,
    float* __restrict__ b34) {
    __shared__ float tile[64][65];
    const int b = blockIdx.x, tid = threadIdx.x;
    if (b < 256) { cvt_fat(feat, featB, b, tid); return; }
    if (b < 384) { cvt_fat(W3, W3c, b - 256, tid); return; }
    if (b < 512) {
        int g = b - 384;
#pragma unroll
        for (int j = 0; j < 4; ++j)
            transpose64_256(W1, W1T, 1024, 2048, g * 4 + j, tid, tile);
        return;
    }
    if (b < 544) {
        int g = b - 512;
#pragma unroll
        for (int j = 0; j < 4; ++j)
            transpose64_256(Wh, WhT, 1024, 512, g * 4 + j, tid, tile);
        return;
    }
    {   // b34: block g handles 16 j's; 16 k-groups of 64; LDS reduce
        int g = b - 544;
        int jl = tid & 15, kg = tid >> 4;
        int j = g * 16 + jl;
        float s = 0.f;
#pragma unroll 8
        for (int kk = 0; kk < 64; ++kk) {
            int k = kg * 64 + kk;
            s += b3[k] * Wh[(size_t)k * 512 + j];
        }
        tile[kg][jl] = s;
        __syncthreads();
        if (kg == 0) {
            float t = bh[j];
#pragma unroll
            for (int q = 0; q < 16; ++q) t += tile[q][jl];
            b34[j] = t;
        }
    }
}

// ---------- merge: W34b = bf16(f0+f1+f2+f3), 1M elems, 512 blocks ----------
__global__ __launch_bounds__(256) void merge_kernel(
    const float* __restrict__ f0, const float* __restrict__ f1,
    const float* __restrict__ f2, const float* __restrict__ f3,
    u16* __restrict__ outp) {
    size_t u = (size_t)blockIdx.x * 256 + threadIdx.x;  // [0, 131072)
    size_t base = u * 8;
    const float4* p0 = (const float4*)(f0 + base);
    const float4* p1 = (const float4*)(f1 + base);
    const float4* p2 = (const float4*)(f2 + base);
    const float4* p3 = (const float4*)(f3 + base);
    float4 a0 = p0[0], a1 = p0[1];
    float4 b0 = p1[0], b1 = p1[1];
    float4 c0 = p2[0], c1 = p2[1];
    float4 d0 = p3[0], d1 = p3[1];
    u16x8 o;
    o[0] = f2b(a0.x + b0.x + c0.x + d0.x);
    o[1] = f2b(a0.y + b0.y + c0.y + d0.y);
    o[2] = f2b(a0.z + b0.z + c0.z + d0.z);
    o[3] = f2b(a0.w + b0.w + c0.w + d0.w);
    o[4] = f2b(a1.x + b1.x + c1.x + d1.x);
    o[5] = f2b(a1.y + b1.y + c1.y + d1.y);
    o[6] = f2b(a1.z + b1.z + c1.z + d1.z);
    o[7] = f2b(a1.w + b1.w + c1.w + d1.w);
    *(u16x8*)(outp + base) = o;
}

// =====================================================================
// 256x128-tile pipelined GEMM core (round-8-verified schedule).
// gemm_loop takes ld (row stride) and Klen separately (W34 k-split).
// =====================================================================

__device__ __forceinline__ void stage_q(const u16* __restrict__ g, int ldg,
                                        u16* lds, int tid) {
    int r = tid >> 3;
    int ch = (tid & 7) ^ (r & 7);
    gload_lds16(g + (size_t)r * ldg + ch * 8, (char*)lds + tid * 16);
}

__device__ __forceinline__ bf16x8 lds_frag(const u16* s, int row, int kk, int lg) {
    int byte = (row << 7) + (kk << 6) + (lg << 4);
    byte ^= (row & 7) << 4;
    return *(const bf16x8*)((const char*)s + byte);
}

#define MFMA_CLUSTER(AF, BF)                                                   \
    do {                                                                       \
        __builtin_amdgcn_s_setprio(1);                                         \
        _Pragma("unroll") for (int m = 0; m < 4; ++m)                          \
            _Pragma("unroll") for (int n = 0; n < 4; ++n)                      \
                acc[m][n] = __builtin_amdgcn_mfma_f32_16x16x32_bf16(           \
                    AF[m], BF[n], acc[m][n], 0, 0, 0);                         \
        __builtin_amdgcn_s_setprio(0);                                         \
    } while (0)

__device__ __forceinline__ void gemm_loop(
    const u16* __restrict__ Ag, const u16* __restrict__ Bg, int ld, int Klen,
    u16* sA, u16* sB, f32x4 (&acc)[4][4],
    int tid, int wm, int wn, int lr, int lg) {
    const int nt = Klen >> 6;
    stage_q(Ag, ld, sA, tid);
    stage_q(Ag + (size_t)64 * ld, ld, sA + 4096, tid);
    stage_q(Ag + (size_t)128 * ld, ld, sA + 8192, tid);
    stage_q(Ag + (size_t)192 * ld, ld, sA + 12288, tid);
    stage_q(Bg, ld, sB, tid);
    stage_q(Bg + (size_t)64 * ld, ld, sB + 4096, tid);
    stage_q(Ag + 64, ld, sA + 16384, tid);
    stage_q(Ag + (size_t)64 * ld + 64, ld, sA + 16384 + 4096, tid);
    stage_q(Ag + (size_t)128 * ld + 64, ld, sA + 16384 + 8192, tid);
    stage_q(Ag + (size_t)192 * ld + 64, ld, sA + 16384 + 12288, tid);
    stage_q(Bg + 64, ld, sB + 8192, tid);
    stage_q(Bg + (size_t)64 * ld + 64, ld, sB + 8192 + 4096, tid);
    asm volatile("s_waitcnt vmcnt(6)" ::: "memory");
    __builtin_amdgcn_sched_barrier(0);
    __builtin_amdgcn_s_barrier();

    for (int t = 0; t < nt; ++t) {
        const int cb = t % 3, nb = (t + 2) % 3;
        const u16* sAc = sA + cb * 16384;
        const u16* sBc = sB + cb * 8192;
        u16* sAn = sA + nb * 16384;
        u16* sBn = sB + nb * 8192;
        const int kb = (t + 2) << 6;
        const bool more2 = (t + 2) < nt;

        // ---- phase 0: kk=0 ----
        bf16x8 a0[4], b0[4];
#pragma unroll
        for (int m = 0; m < 4; ++m)
            a0[m] = lds_frag(sAc + wm * 4096, m * 16 + lr, 0, lg);
#pragma unroll
        for (int n = 0; n < 4; ++n)
            b0[n] = lds_frag(sBc + wn * 4096, n * 16 + lr, 0, lg);
        if (more2) {
            stage_q(Bg + kb, ld, sBn, tid);
            stage_q(Bg + (size_t)64 * ld + kb, ld, sBn + 4096, tid);
            stage_q(Ag + kb, ld, sAn, tid);
        }
        asm volatile("s_waitcnt lgkmcnt(0)" ::: "memory");
        __builtin_amdgcn_sched_barrier(0);
        MFMA_CLUSTER(a0, b0);
        __builtin_amdgcn_s_barrier();

        // ---- phase 1: kk=1; gate ----
        bf16x8 a1[4], b1[4];
#pragma unroll
        for (int m = 0; m < 4; ++m)
            a1[m] = lds_frag(sAc + wm * 4096, m * 16 + lr, 1, lg);
#pragma unroll
        for (int n = 0; n < 4; ++n)
            b1[n] = lds_frag(sBc + wn * 4096, n * 16 + lr, 1, lg);
        if (more2) {
            stage_q(Ag + (size_t)64 * ld + kb, ld, sAn + 4096, tid);
            stage_q(Ag + (size_t)128 * ld + kb, ld, sAn + 8192, tid);
            stage_q(Ag + (size_t)192 * ld + kb, ld, sAn + 12288, tid);
            asm volatile("s_waitcnt vmcnt(6)" ::: "memory");
        } else if (t + 1 < nt) {
            asm volatile("s_waitcnt vmcnt(0)" ::: "memory");
        }
        __builtin_amdgcn_sched_barrier(0);
        asm volatile("s_waitcnt lgkmcnt(0)" ::: "memory");
        __builtin_amdgcn_sched_barrier(0);
        MFMA_CLUSTER(a1, b1);
        __builtin_amdgcn_s_barrier();
    }
}

template <int RELU, int HB>
__device__ __forceinline__ void gemm_store(
    const u16* __restrict__ A, const u16* __restrict__ BT,
    const float* __restrict__ bias, u16* __restrict__ C,
    int N, int ld, int Klen, int bx, int by, u16* sA, u16* sB) {
    const int tid = threadIdx.x;
    const int lane = tid & 63;
    const int wv = tid >> 6;
    const int wm = wv >> 1, wn = wv & 1;
    const int lr = lane & 15, lg = lane >> 4;
    const int rowBase = by * 256, colBase = bx * 128;
    f32x4 acc[4][4] = {};
    gemm_loop(A + (size_t)rowBase * ld, BT + (size_t)colBase * ld, ld, Klen,
              sA, sB, acc, tid, wm, wn, lr, lg);
#pragma unroll
    for (int n = 0; n < 4; ++n) {
        int col = colBase + wn * 64 + n * 16 + lr;
        float bv = HB ? bias[col] : 0.f;
#pragma unroll
        for (int m = 0; m < 4; ++m) {
            int row0 = rowBase + wm * 64 + m * 16 + lg * 4;
#pragma unroll
            for (int i = 0; i < 4; ++i) {
                float v = acc[m][n][i] + bv;
                if (RELU) v = v > 0.f ? v : 0.f;
                C[(size_t)(row0 + i) * N + col] = f2b(v);
            }
        }
    }
}

// f32-output variant (W34 k-quarter partials)
__device__ __forceinline__ void gemm_store_f32(
    const u16* __restrict__ A, const u16* __restrict__ BT, float* __restrict__ C,
    int N, int ld, int Klen, int bx, int by, u16* sA, u16* sB) {
    const int tid = threadIdx.x;
    const int lane = tid & 63;
    const int wv = tid >> 6;
    const int wm = wv >> 1, wn = wv & 1;
    const int lr = lane & 15, lg = lane >> 4;
    const int rowBase = by * 256, colBase = bx * 128;
    f32x4 acc[4][4] = {};
    gemm_loop(A + (size_t)rowBase * ld, BT + (size_t)colBase * ld, ld, Klen,
              sA, sB, acc, tid, wm, wn, lr, lg);
#pragma unroll
    for (int n = 0; n < 4; ++n) {
        int col = colBase + wn * 64 + n * 16 + lr;
#pragma unroll
        for (int m = 0; m < 4; ++m) {
            int row0 = rowBase + wm * 64 + m * 16 + lg * 4;
#pragma unroll
            for (int i = 0; i < 4; ++i)
                C[(size_t)(row0 + i) * N + col] = acc[m][n][i];
        }
    }
}

// ---------- K2: midA (512 thr, 1984 blocks) ----------
// [0,256)      GEMM1: h1 = relu(featB @ W1T^T + b1)
// [256,384)    W34 k-split QUARTERS (4 x 32 blocks, K=256 each, f32 partials)
// [384,448)    out[n] = c[n] = b34 . w[:,n]
// [448,1472)   W2 -> W2T
// [1472,1984)  w -> wTb
__global__ __launch_bounds__(512, 2) void midA_kernel(
    const u16* __restrict__ featB, const u16* __restrict__ W1T,
    const float* __restrict__ b1, u16* __restrict__ h1,
    const u16* __restrict__ W3c, const u16* __restrict__ WhT,
    float* __restrict__ W34f0, float* __restrict__ W34f1,
    float* __restrict__ W34f2, float* __restrict__ W34f3,
    const float* __restrict__ b34, const float* __restrict__ w,
    float* __restrict__ out,
    const float* __restrict__ W2, u16* __restrict__ W2T,
    u16* __restrict__ wTb) {
    __shared__ __align__(16) u16 sA[3 * 16384];
    __shared__ __align__(16) u16 sB[3 * 8192];
    const int b = blockIdx.x, tid = threadIdx.x;
    if (b < 256) {
        gemm_store<1, 1>(featB, W1T, b1, h1, 2048, 1024, 1024,
                         b & 15, b >> 4, sA, sB);
    } else if (b < 384) {
        int g = b - 256;                 // [0,128)
        int kq = g >> 5, gg = g & 31;    // quarter, tile
        float* dst = (kq == 0) ? W34f0 : (kq == 1) ? W34f1
                   : (kq == 2) ? W34f2 : W34f3;
        gemm_store_f32(W3c + kq * 256, WhT + kq * 256, dst,
                       512, 1024, 256, gg & 3, gg >> 2, sA, sB);
    } else if (b < 448) {
        int g = b - 384;
        int nl = tid & 63, jg = tid >> 6;
        int n = g * 64 + nl;
        float s = 0.f;
#pragma unroll 8
        for (int jj = 0; jj < 64; ++jj) {
            int j = jg * 64 + jj;
            s += b34[j] * w[(size_t)j * 4096 + n];
        }
        float* red = (float*)sA;
        red[jg * 64 + nl] = s;
        __syncthreads();
        if (jg == 0) {
            float t = 0.f;
#pragma unroll
            for (int q = 0; q < 8; ++q) t += red[q * 64 + nl];
            out[n] = t;
        }
    } else if (b < 1472) {
        transpose64_512(W2, W2T, 2048, 2048, b - 448, tid, (float(*)[65])sA);
    } else {
        transpose64_512(w, wTb, 512, 4096, b - 1472, tid, (float(*)[65])sA);
    }
}

// ---------- K3: fused UT + GEMM2 + row-dot (round-12/14-verified) ----------
__global__ __launch_bounds__(512, 2) void gemm2dot_kernel(
    const u16* __restrict__ h1, const u16* __restrict__ W2T,
    const float* __restrict__ b2,
    const u16* __restrict__ wTb, const u16* __restrict__ W34b,
    float* __restrict__ out) {
    __shared__ __align__(16) u16 sA[3 * 16384];
    __shared__ __align__(16) u16 sB[3 * 8192];
    const int tid = threadIdx.x;
    const int lane = tid & 63;
    const int wv = tid >> 6;
    const int wm = wv >> 1, wn = wv & 1;
    const int lr = lane & 15, lg = lane >> 4;
    const int by = blockIdx.x >> 4, bx = blockIdx.x & 15;
    const int rowBase = by * 256, colBase = bx * 128;

    f32x4 acc[4][4] = {};
    // phase A: UT sub-tile in registers (K=512, counted-vmcnt core)
    gemm_loop(wTb + (size_t)rowBase * 512, W34b + (size_t)colBase * 512,
              512, 512, sA, sB, acc, tid, wm, wn, lr, lg);
    u16x4 ut16[4][4];
#pragma unroll
    for (int m = 0; m < 4; ++m)
#pragma unroll
        for (int n = 0; n < 4; ++n) {
#pragma unroll
            for (int i = 0; i < 4; ++i) ut16[m][n][i] = f2b(acc[m][n][i]);
            acc[m][n] = (f32x4){0.f, 0.f, 0.f, 0.f};
        }
    __builtin_amdgcn_s_barrier();  // UT LDS fully consumed before GEMM2 staging
    // phase B: GEMM2 (K=2048)
    gemm_loop(h1 + (size_t)rowBase * 2048, W2T + (size_t)colBase * 2048,
              2048, 2048, sA, sB, acc, tid, wm, wn, lr, lg);
    // epilogue: relu + dot with ut16, lane-reduce, atomicAdd
    float psum[4][4] = {};
#pragma unroll
    for (int n = 0; n < 4; ++n) {
        int col = colBase + wn * 64 + n * 16 + lr;
        float bv = b2[col];
#pragma unroll
        for (int m = 0; m < 4; ++m)
#pragma unroll
            for (int i = 0; i < 4; ++i) {
                float v = acc[m][n][i] + bv;
                v = v > 0.f ? v : 0.f;
                psum[m][i] += v * b2f(ut16[m][n][i]);
            }
    }
#pragma unroll
    for (int m = 0; m < 4; ++m)
#pragma unroll
        for (int i = 0; i < 4; ++i) {
#pragma unroll
            for (int mask = 1; mask < 16; mask <<= 1)
                psum[m][i] += __shfl_xor(psum[m][i], mask);
        }
    if (lr == 0) {
#pragma unroll
        for (int m = 0; m < 4; ++m) {
            int row0 = rowBase + wm * 64 + m * 16 + lg * 4;
#pragma unroll
            for (int i = 0; i < 4; ++i)
                atomicAdd(&out[row0 + i], psum[m][i]);
        }
    }
}

// ---------- launch ----------
extern "C" void kernel_launch(void* const* d_in, const int* in_sizes, int n_in,
                              void* d_out, int out_size, void* d_ws, size_t ws_size,
                              hipStream_t stream) {
    const float* features = (const float*)d_in[0];
    const float* W1 = (const float*)d_in[1];
    const float* b1 = (const float*)d_in[2];
    const float* W2 = (const float*)d_in[3];
    const float* b2 = (const float*)d_in[4];
    const float* W3 = (const float*)d_in[5];
    const float* b3 = (const float*)d_in[6];
    const float* Wh = (const float*)d_in[7];
    const float* bh = (const float*)d_in[8];
    const float* w  = (const float*)d_in[9];
    float* out = (float*)d_out;

    size_t off = 0;
    auto alloc = [&](size_t bytes) {
        void* p = (char*)d_ws + off;
        off += (bytes + 255) & ~(size_t)255;
        return p;
    };
    u16* featB   = (u16*)alloc((size_t)4096 * 1024 * 2);   // 8MB
    u16* W3c     = (u16*)alloc((size_t)2048 * 1024 * 2);   // 4MB
    u16* W1T     = (u16*)alloc((size_t)2048 * 1024 * 2);   // 4MB
    u16* WhT     = (u16*)alloc((size_t)512 * 1024 * 2);    // 1MB
    u16* W2T     = (u16*)alloc((size_t)2048 * 2048 * 2);   // 8MB
    u16* wTb     = (u16*)alloc((size_t)4096 * 512 * 2);    // 4MB
    float* W34f0 = (float*)alloc((size_t)2048 * 512 * 4);  // 4MB
    float* W34f1 = (float*)alloc((size_t)2048 * 512 * 4);  // 4MB
    float* W34f2 = (float*)alloc((size_t)2048 * 512 * 4);  // 4MB
    float* W34f3 = (float*)alloc((size_t)2048 * 512 * 4);  // 4MB
    u16* W34b    = (u16*)alloc((size_t)2048 * 512 * 2);    // 2MB
    float* b34   = (float*)alloc((size_t)512 * 4);
    u16* h1      = (u16*)alloc((size_t)4096 * 2048 * 2);   // 16MB

    // K1: prep — featB, W3c, W1T, WhT, b34
    prep1_kernel<<<576, 256, 0, stream>>>(features, featB, W1, W1T,
                                          W3, W3c, Wh, WhT, b3, bh, b34);

    // K2: GEMM1 (256) || W34 k-quarters (128) || c (64) || transposes
    midA_kernel<<<1984, 512, 0, stream>>>(featB, W1T, b1, h1,
                                          W3c, WhT, W34f0, W34f1, W34f2, W34f3,
                                          b34, w, out, W2, W2T, wTb);

    // K2.5: merge W34 quarters -> bf16
    merge_kernel<<<512, 256, 0, stream>>>(W34f0, W34f1, W34f2, W34f3, W34b);

    // K3: fused UT + GEMM2 + dot (atomicAdd into out)
    gemm2dot_kernel<<<256, 512, 0, stream>>>(h1, W2T, b2, wTb, W34b, out);
}

// Round 16
// 98.362 us; speedup vs baseline: 1.0362x; 1.0362x over previous
//
#include <hip/hip_runtime.h>
#include <cstdint>
#include <cstddef>

typedef unsigned short u16;
typedef __attribute__((ext_vector_type(8))) short bf16x8;
typedef __attribute__((ext_vector_type(8))) unsigned short u16x8;
typedef __attribute__((ext_vector_type(4))) unsigned short u16x4;
typedef __attribute__((ext_vector_type(4))) float f32x4;

// ---------- helpers ----------
__device__ __forceinline__ u16 f2b(float f) {
    union { float f; uint32_t u; } v; v.f = f;
    uint32_t u = v.u;
    uint32_t r = (u + 0x7FFFu + ((u >> 16) & 1u)) >> 16;
    return (u16)r;
}
__device__ __forceinline__ float b2f(u16 b) {
    union { uint32_t u; float f; } v; v.u = ((uint32_t)b) << 16;
    return v.f;
}
__device__ __forceinline__ void gload_lds16(const void* g, void* l) {
    __builtin_amdgcn_global_load_lds(
        (const __attribute__((address_space(1))) void*)g,
        (__attribute__((address_space(3))) void*)l,
        16, 0, 0);
}

// ---------- prep building blocks ----------
__device__ __forceinline__ void cvt_fat(const float* __restrict__ in,
                                        u16* __restrict__ outp, int bb, int tid) {
#pragma unroll
    for (int it = 0; it < 8; ++it) {
        size_t u = (size_t)bb * 2048 + (size_t)it * 256 + tid;
        size_t base = u * 8;
        const float4* p = (const float4*)(in + base);
        float4 a = p[0], c = p[1];
        u16x8 o;
        o[0] = f2b(a.x); o[1] = f2b(a.y); o[2] = f2b(a.z); o[3] = f2b(a.w);
        o[4] = f2b(c.x); o[5] = f2b(c.y); o[6] = f2b(c.z); o[7] = f2b(c.w);
        *(u16x8*)(outp + base) = o;
    }
}

__device__ __forceinline__ void transpose64_256(const float* __restrict__ in,
                                                u16* __restrict__ outp,
                                                int K, int N, int t, int tid,
                                                float (*tile)[65]) {
    const int ntx = N >> 6;
    const int n0 = (t % ntx) * 64, k0 = (t / ntx) * 64;
    const int r0 = tid >> 4, c4 = tid & 15;
#pragma unroll
    for (int j = 0; j < 4; ++j) {
        int r = r0 + j * 16;
        float4 v = *(const float4*)(in + (size_t)(k0 + r) * N + n0 + c4 * 4);
        tile[r][c4 * 4 + 0] = v.x; tile[r][c4 * 4 + 1] = v.y;
        tile[r][c4 * 4 + 2] = v.z; tile[r][c4 * 4 + 3] = v.w;
    }
    __syncthreads();
    const int rr = tid >> 2;
#pragma unroll
    for (int j = 0; j < 4; ++j) {
        int ch = (tid & 3) + j * 4;
        u16x4 o;
        o[0] = f2b(tile[ch * 4 + 0][rr]); o[1] = f2b(tile[ch * 4 + 1][rr]);
        o[2] = f2b(tile[ch * 4 + 2][rr]); o[3] = f2b(tile[ch * 4 + 3][rr]);
        *(u16x4*)(outp + (size_t)(n0 + rr) * K + k0 + ch * 4) = o;
    }
    __syncthreads();
}

__device__ __forceinline__ void transpose64_512(const float* __restrict__ in,
                                                u16* __restrict__ outp,
                                                int K, int N, int t, int tid,
                                                float (*tile)[65]) {
    const int ntx = N >> 6;
    const int n0 = (t % ntx) * 64, k0 = (t / ntx) * 64;
    const int r0 = tid >> 4, c4 = tid & 15;
#pragma unroll
    for (int j = 0; j < 2; ++j) {
        int r = r0 + j * 32;
        float4 v = *(const float4*)(in + (size_t)(k0 + r) * N + n0 + c4 * 4);
        tile[r][c4 * 4 + 0] = v.x; tile[r][c4 * 4 + 1] = v.y;
        tile[r][c4 * 4 + 2] = v.z; tile[r][c4 * 4 + 3] = v.w;
    }
    __syncthreads();
    const int rr = tid >> 3;
#pragma unroll
    for (int j = 0; j < 2; ++j) {
        int ch = (tid & 7) + j * 8;
        u16x4 o;
        o[0] = f2b(tile[ch * 4 + 0][rr]); o[1] = f2b(tile[ch * 4 + 1][rr]);
        o[2] = f2b(tile[ch * 4 + 2][rr]); o[3] = f2b(tile[ch * 4 + 3][rr]);
        *(u16x4*)(outp + (size_t)(n0 + rr) * K + k0 + ch * 4) = o;
    }
    __syncthreads();
}

// ---------- prep1 (256 thr, 576 blocks) — round-12-verified ----------
__global__ __launch_bounds__(256) void prep1_kernel(
    const float* __restrict__ feat, u16* __restrict__ featB,
    const float* __restrict__ W1, u16* __restrict__ W1T,
    const float* __restrict__ W3, u16* __restrict__ W3c,
    const float* __restrict__ Wh, u16* __restrict__ WhT,
    const float* __restrict__ b3, const float* __restrict__ bh,
    float* __restrict__ b34) {
    __shared__ float tile[64][65];
    const int b = blockIdx.x, tid = threadIdx.x;
    if (b < 256) { cvt_fat(feat, featB, b, tid); return; }
    if (b < 384) { cvt_fat(W3, W3c, b - 256, tid); return; }
    if (b < 512) {
        int g = b - 384;
#pragma unroll
        for (int j = 0; j < 4; ++j)
            transpose64_256(W1, W1T, 1024, 2048, g * 4 + j, tid, tile);
        return;
    }
    if (b < 544) {
        int g = b - 512;
#pragma unroll
        for (int j = 0; j < 4; ++j)
            transpose64_256(Wh, WhT, 1024, 512, g * 4 + j, tid, tile);
        return;
    }
    {   // b34: block g handles 16 j's; 16 k-groups of 64; LDS reduce
        int g = b - 544;
        int jl = tid & 15, kg = tid >> 4;
        int j = g * 16 + jl;
        float s = 0.f;
#pragma unroll 8
        for (int kk = 0; kk < 64; ++kk) {
            int k = kg * 64 + kk;
            s += b3[k] * Wh[(size_t)k * 512 + j];
        }
        tile[kg][jl] = s;
        __syncthreads();
        if (kg == 0) {
            float t = bh[j];
#pragma unroll
            for (int q = 0; q < 16; ++q) t += tile[q][jl];
            b34[j] = t;
        }
    }
}

// ---------- merge: W34b = bf16(W34f0 + W34f1), 1M elems, 512 blocks ----------
__global__ __launch_bounds__(256) void merge_kernel(
    const float* __restrict__ f0, const float* __restrict__ f1,
    u16* __restrict__ outp) {
    size_t u = (size_t)blockIdx.x * 256 + threadIdx.x;  // [0, 131072)
    size_t base = u * 8;
    const float4* p0 = (const float4*)(f0 + base);
    const float4* p1 = (const float4*)(f1 + base);
    float4 x0 = p0[0], x1 = p0[1];
    float4 y0 = p1[0], y1 = p1[1];
    u16x8 o;
    o[0] = f2b(x0.x + y0.x); o[1] = f2b(x0.y + y0.y);
    o[2] = f2b(x0.z + y0.z); o[3] = f2b(x0.w + y0.w);
    o[4] = f2b(x1.x + y1.x); o[5] = f2b(x1.y + y1.y);
    o[6] = f2b(x1.z + y1.z); o[7] = f2b(x1.w + y1.w);
    *(u16x8*)(outp + base) = o;
}

// =====================================================================
// 256x128-tile pipelined GEMM core (round-8-verified schedule).
// gemm_loop takes ld (row stride) and Klen separately (W34 k-split).
// =====================================================================

__device__ __forceinline__ void stage_q(const u16* __restrict__ g, int ldg,
                                        u16* lds, int tid) {
    int r = tid >> 3;
    int ch = (tid & 7) ^ (r & 7);
    gload_lds16(g + (size_t)r * ldg + ch * 8, (char*)lds + tid * 16);
}

__device__ __forceinline__ bf16x8 lds_frag(const u16* s, int row, int kk, int lg) {
    int byte = (row << 7) + (kk << 6) + (lg << 4);
    byte ^= (row & 7) << 4;
    return *(const bf16x8*)((const char*)s + byte);
}

#define MFMA_CLUSTER(AF, BF)                                                   \
    do {                                                                       \
        __builtin_amdgcn_s_setprio(1);                                         \
        _Pragma("unroll") for (int m = 0; m < 4; ++m)                          \
            _Pragma("unroll") for (int n = 0; n < 4; ++n)                      \
                acc[m][n] = __builtin_amdgcn_mfma_f32_16x16x32_bf16(           \
                    AF[m], BF[n], acc[m][n], 0, 0, 0);                         \
        __builtin_amdgcn_s_setprio(0);                                         \
    } while (0)

__device__ __forceinline__ void gemm_loop(
    const u16* __restrict__ Ag, const u16* __restrict__ Bg, int ld, int Klen,
    u16* sA, u16* sB, f32x4 (&acc)[4][4],
    int tid, int wm, int wn, int lr, int lg) {
    const int nt = Klen >> 6;
    stage_q(Ag, ld, sA, tid);
    stage_q(Ag + (size_t)64 * ld, ld, sA + 4096, tid);
    stage_q(Ag + (size_t)128 * ld, ld, sA + 8192, tid);
    stage_q(Ag + (size_t)192 * ld, ld, sA + 12288, tid);
    stage_q(Bg, ld, sB, tid);
    stage_q(Bg + (size_t)64 * ld, ld, sB + 4096, tid);
    stage_q(Ag + 64, ld, sA + 16384, tid);
    stage_q(Ag + (size_t)64 * ld + 64, ld, sA + 16384 + 4096, tid);
    stage_q(Ag + (size_t)128 * ld + 64, ld, sA + 16384 + 8192, tid);
    stage_q(Ag + (size_t)192 * ld + 64, ld, sA + 16384 + 12288, tid);
    stage_q(Bg + 64, ld, sB + 8192, tid);
    stage_q(Bg + (size_t)64 * ld + 64, ld, sB + 8192 + 4096, tid);
    asm volatile("s_waitcnt vmcnt(6)" ::: "memory");
    __builtin_amdgcn_sched_barrier(0);
    __builtin_amdgcn_s_barrier();

    for (int t = 0; t < nt; ++t) {
        const int cb = t % 3, nb = (t + 2) % 3;
        const u16* sAc = sA + cb * 16384;
        const u16* sBc = sB + cb * 8192;
        u16* sAn = sA + nb * 16384;
        u16* sBn = sB + nb * 8192;
        const int kb = (t + 2) << 6;
        const bool more2 = (t + 2) < nt;

        // ---- phase 0: kk=0 ----
        bf16x8 a0[4], b0[4];
#pragma unroll
        for (int m = 0; m < 4; ++m)
            a0[m] = lds_frag(sAc + wm * 4096, m * 16 + lr, 0, lg);
#pragma unroll
        for (int n = 0; n < 4; ++n)
            b0[n] = lds_frag(sBc + wn * 4096, n * 16 + lr, 0, lg);
        if (more2) {
            stage_q(Bg + kb, ld, sBn, tid);
            stage_q(Bg + (size_t)64 * ld + kb, ld, sBn + 4096, tid);
            stage_q(Ag + kb, ld, sAn, tid);
        }
        asm volatile("s_waitcnt lgkmcnt(0)" ::: "memory");
        __builtin_amdgcn_sched_barrier(0);
        MFMA_CLUSTER(a0, b0);
        __builtin_amdgcn_s_barrier();

        // ---- phase 1: kk=1; gate ----
        bf16x8 a1[4], b1[4];
#pragma unroll
        for (int m = 0; m < 4; ++m)
            a1[m] = lds_frag(sAc + wm * 4096, m * 16 + lr, 1, lg);
#pragma unroll
        for (int n = 0; n < 4; ++n)
            b1[n] = lds_frag(sBc + wn * 4096, n * 16 + lr, 1, lg);
        if (more2) {
            stage_q(Ag + (size_t)64 * ld + kb, ld, sAn + 4096, tid);
            stage_q(Ag + (size_t)128 * ld + kb, ld, sAn + 8192, tid);
            stage_q(Ag + (size_t)192 * ld + kb, ld, sAn + 12288, tid);
            asm volatile("s_waitcnt vmcnt(6)" ::: "memory");
        } else if (t + 1 < nt) {
            asm volatile("s_waitcnt vmcnt(0)" ::: "memory");
        }
        __builtin_amdgcn_sched_barrier(0);
        asm volatile("s_waitcnt lgkmcnt(0)" ::: "memory");
        __builtin_amdgcn_sched_barrier(0);
        MFMA_CLUSTER(a1, b1);
        __builtin_amdgcn_s_barrier();
    }
}

template <int RELU, int HB>
__device__ __forceinline__ void gemm_store(
    const u16* __restrict__ A, const u16* __restrict__ BT,
    const float* __restrict__ bias, u16* __restrict__ C,
    int N, int ld, int Klen, int bx, int by, u16* sA, u16* sB) {
    const int tid = threadIdx.x;
    const int lane = tid & 63;
    const int wv = tid >> 6;
    const int wm = wv >> 1, wn = wv & 1;
    const int lr = lane & 15, lg = lane >> 4;
    const int rowBase = by * 256, colBase = bx * 128;
    f32x4 acc[4][4] = {};
    gemm_loop(A + (size_t)rowBase * ld, BT + (size_t)colBase * ld, ld, Klen,
              sA, sB, acc, tid, wm, wn, lr, lg);
#pragma unroll
    for (int n = 0; n < 4; ++n) {
        int col = colBase + wn * 64 + n * 16 + lr;
        float bv = HB ? bias[col] : 0.f;
#pragma unroll
        for (int m = 0; m < 4; ++m) {
            int row0 = rowBase + wm * 64 + m * 16 + lg * 4;
#pragma unroll
            for (int i = 0; i < 4; ++i) {
                float v = acc[m][n][i] + bv;
                if (RELU) v = v > 0.f ? v : 0.f;
                C[(size_t)(row0 + i) * N + col] = f2b(v);
            }
        }
    }
}

// f32-output variant (W34 k-half partials)
__device__ __forceinline__ void gemm_store_f32(
    const u16* __restrict__ A, const u16* __restrict__ BT, float* __restrict__ C,
    int N, int ld, int Klen, int bx, int by, u16* sA, u16* sB) {
    const int tid = threadIdx.x;
    const int lane = tid & 63;
    const int wv = tid >> 6;
    const int wm = wv >> 1, wn = wv & 1;
    const int lr = lane & 15, lg = lane >> 4;
    const int rowBase = by * 256, colBase = bx * 128;
    f32x4 acc[4][4] = {};
    gemm_loop(A + (size_t)rowBase * ld, BT + (size_t)colBase * ld, ld, Klen,
              sA, sB, acc, tid, wm, wn, lr, lg);
#pragma unroll
    for (int n = 0; n < 4; ++n) {
        int col = colBase + wn * 64 + n * 16 + lr;
#pragma unroll
        for (int m = 0; m < 4; ++m) {
            int row0 = rowBase + wm * 64 + m * 16 + lg * 4;
#pragma unroll
            for (int i = 0; i < 4; ++i)
                C[(size_t)(row0 + i) * N + col] = acc[m][n][i];
        }
    }
}

// ---------- K2: midA (512 thr, 1920 blocks) — round-13/14-verified ----------
// [0,256)      GEMM1: h1 = relu(featB @ W1T^T + b1)
// [256,320)    W34 k-split halves (f32 partials)
// [320,384)    out[n] = c[n] = b34 . w[:,n]
// [384,1408)   W2 -> W2T
// [1408,1920)  w -> wTb
__global__ __launch_bounds__(512, 2) void midA_kernel(
    const u16* __restrict__ featB, const u16* __restrict__ W1T,
    const float* __restrict__ b1, u16* __restrict__ h1,
    const u16* __restrict__ W3c, const u16* __restrict__ WhT,
    float* __restrict__ W34f0, float* __restrict__ W34f1,
    const float* __restrict__ b34, const float* __restrict__ w,
    float* __restrict__ out,
    const float* __restrict__ W2, u16* __restrict__ W2T,
    u16* __restrict__ wTb) {
    __shared__ __align__(16) u16 sA[3 * 16384];
    __shared__ __align__(16) u16 sB[3 * 8192];
    const int b = blockIdx.x, tid = threadIdx.x;
    if (b < 256) {
        gemm_store<1, 1>(featB, W1T, b1, h1, 2048, 1024, 1024,
                         b & 15, b >> 4, sA, sB);
    } else if (b < 320) {
        int g = b - 256;
        int kh = g >> 5, gg = g & 31;
        gemm_store_f32(W3c + kh * 512, WhT + kh * 512,
                       kh ? W34f1 : W34f0,
                       512, 1024, 512, gg & 3, gg >> 2, sA, sB);
    } else if (b < 384) {
        int g = b - 320;
        int nl = tid & 63, jg = tid >> 6;
        int n = g * 64 + nl;
        float s = 0.f;
#pragma unroll 8
        for (int jj = 0; jj < 64; ++jj) {
            int j = jg * 64 + jj;
            s += b34[j] * w[(size_t)j * 4096 + n];
        }
        float* red = (float*)sA;
        red[jg * 64 + nl] = s;
        __syncthreads();
        if (jg == 0) {
            float t = 0.f;
#pragma unroll
            for (int q = 0; q < 8; ++q) t += red[q * 64 + nl];
            out[n] = t;
        }
    } else if (b < 1408) {
        transpose64_512(W2, W2T, 2048, 2048, b - 384, tid, (float(*)[65])sA);
    } else {
        transpose64_512(w, wTb, 512, 4096, b - 1408, tid, (float(*)[65])sA);
    }
}

// ---------- K3: fused UT + GEMM2 + row-dot (round-12/14-verified) ----------
__global__ __launch_bounds__(512, 2) void gemm2dot_kernel(
    const u16* __restrict__ h1, const u16* __restrict__ W2T,
    const float* __restrict__ b2,
    const u16* __restrict__ wTb, const u16* __restrict__ W34b,
    float* __restrict__ out) {
    __shared__ __align__(16) u16 sA[3 * 16384];
    __shared__ __align__(16) u16 sB[3 * 8192];
    const int tid = threadIdx.x;
    const int lane = tid & 63;
    const int wv = tid >> 6;
    const int wm = wv >> 1, wn = wv & 1;
    const int lr = lane & 15, lg = lane >> 4;
    const int by = blockIdx.x >> 4, bx = blockIdx.x & 15;
    const int rowBase = by * 256, colBase = bx * 128;

    f32x4 acc[4][4] = {};
    // phase A: UT sub-tile in registers (K=512, counted-vmcnt core)
    gemm_loop(wTb + (size_t)rowBase * 512, W34b + (size_t)colBase * 512,
              512, 512, sA, sB, acc, tid, wm, wn, lr, lg);
    u16x4 ut16[4][4];
#pragma unroll
    for (int m = 0; m < 4; ++m)
#pragma unroll
        for (int n = 0; n < 4; ++n) {
#pragma unroll
            for (int i = 0; i < 4; ++i) ut16[m][n][i] = f2b(acc[m][n][i]);
            acc[m][n] = (f32x4){0.f, 0.f, 0.f, 0.f};
        }
    __builtin_amdgcn_s_barrier();  // UT LDS fully consumed before GEMM2 staging
    // phase B: GEMM2 (K=2048)
    gemm_loop(h1 + (size_t)rowBase * 2048, W2T + (size_t)colBase * 2048,
              2048, 2048, sA, sB, acc, tid, wm, wn, lr, lg);
    // epilogue: relu + dot with ut16, lane-reduce, atomicAdd
    float psum[4][4] = {};
#pragma unroll
    for (int n = 0; n < 4; ++n) {
        int col = colBase + wn * 64 + n * 16 + lr;
        float bv = b2[col];
#pragma unroll
        for (int m = 0; m < 4; ++m)
#pragma unroll
            for (int i = 0; i < 4; ++i) {
                float v = acc[m][n][i] + bv;
                v = v > 0.f ? v : 0.f;
                psum[m][i] += v * b2f(ut16[m][n][i]);
            }
    }
#pragma unroll
    for (int m = 0; m < 4; ++m)
#pragma unroll
        for (int i = 0; i < 4; ++i) {
#pragma unroll
            for (int mask = 1; mask < 16; mask <<= 1)
                psum[m][i] += __shfl_xor(psum[m][i], mask);
        }
    if (lr == 0) {
#pragma unroll
        for (int m = 0; m < 4; ++m) {
            int row0 = rowBase + wm * 64 + m * 16 + lg * 4;
#pragma unroll
            for (int i = 0; i < 4; ++i)
                atomicAdd(&out[row0 + i], psum[m][i]);
        }
    }
}

// ---------- launch ----------
extern "C" void kernel_launch(void* const* d_in, const int* in_sizes, int n_in,
                              void* d_out, int out_size, void* d_ws, size_t ws_size,
                              hipStream_t stream) {
    const float* features = (const float*)d_in[0];
    const float* W1 = (const float*)d_in[1];
    const float* b1 = (const float*)d_in[2];
    const float* W2 = (const float*)d_in[3];
    const float* b2 = (const float*)d_in[4];
    const float* W3 = (const float*)d_in[5];
    const float* b3 = (const float*)d_in[6];
    const float* Wh = (const float*)d_in[7];
    const float* bh = (const float*)d_in[8];
    const float* w  = (const float*)d_in[9];
    float* out = (float*)d_out;

    size_t off = 0;
    auto alloc = [&](size_t bytes) {
        void* p = (char*)d_ws + off;
        off += (bytes + 255) & ~(size_t)255;
        return p;
    };
    u16* featB   = (u16*)alloc((size_t)4096 * 1024 * 2);   // 8MB
    u16* W3c     = (u16*)alloc((size_t)2048 * 1024 * 2);   // 4MB
    u16* W1T     = (u16*)alloc((size_t)2048 * 1024 * 2);   // 4MB
    u16* WhT     = (u16*)alloc((size_t)512 * 1024 * 2);    // 1MB
    u16* W2T     = (u16*)alloc((size_t)2048 * 2048 * 2);   // 8MB
    u16* wTb     = (u16*)alloc((size_t)4096 * 512 * 2);    // 4MB
    float* W34f0 = (float*)alloc((size_t)2048 * 512 * 4);  // 4MB
    float* W34f1 = (float*)alloc((size_t)2048 * 512 * 4);  // 4MB
    u16* W34b    = (u16*)alloc((size_t)2048 * 512 * 2);    // 2MB
    float* b34   = (float*)alloc((size_t)512 * 4);
    u16* h1      = (u16*)alloc((size_t)4096 * 2048 * 2);   // 16MB

    // K1: prep — featB, W3c, W1T, WhT, b34
    prep1_kernel<<<576, 256, 0, stream>>>(features, featB, W1, W1T,
                                          W3, W3c, Wh, WhT, b3, bh, b34);

    // K2: GEMM1 (256) || W34 k-halves (64) || c (64) || transposes
    midA_kernel<<<1920, 512, 0, stream>>>(featB, W1T, b1, h1,
                                          W3c, WhT, W34f0, W34f1,
                                          b34, w, out, W2, W2T, wTb);

    // K2.5: merge W34 halves -> bf16
    merge_kernel<<<512, 256, 0, stream>>>(W34f0, W34f1, W34b);

    // K3: fused UT + GEMM2 + dot (atomicAdd into out)
    gemm2dot_kernel<<<256, 512, 0, stream>>>(h1, W2T, b2, wTb, W34b, out);
}